// Round 6
// baseline (782.418 us; speedup 1.0000x reference)
//
#include <hip/hip_runtime.h>
#include <float.h>

#define Nn 32
#define Ll 2048
#define Cc 128
#define NTILES 32
#define TILE 64                 // Ll / NTILES
#define OUTC 1172               // 3*384 + 20
#define NLC (Nn * Ll * Cc)      // 8388608
#define OUT_ELEMS ((size_t)Nn * Ll * OUTC)  // 76808192
#define NUNITS (3 * Nn * NTILES)            // 3072 half-wave units
#define AGG (NUNITS * Cc)                   // 393216 floats per array

typedef float  f4 __attribute__((ext_vector_type(4)));
typedef int    i4 __attribute__((ext_vector_type(4)));

__device__ __forceinline__ void nts4(f4* p, f4 v) { __builtin_nontemporal_store(v, p); }
__device__ __forceinline__ void nts1(float* p, float v) { __builtin_nontemporal_store(v, p); }

// R6: single fused kernel with ticket-ordered decoupled lookback.
// Kills the cold 301 MB x re-read (apply's rescan now hits L1/L2/L3 within us
// of the aggregate pass) and one kernel launch gap. All-NT stores (R3/R5 A/B/C
// showed NT optimal on every output region).

// ---------------- init: zero ticket+flags, run demographics MLP ----------------
__global__ __launch_bounds__(256) void k_init(
        int* __restrict__ counter, int* __restrict__ flags,
        const float* __restrict__ dem, const float* __restrict__ W1,
        const float* __restrict__ b1, const float* __restrict__ W2,
        const float* __restrict__ b2, float* __restrict__ dvals) {
    int tid = threadIdx.x;
    if (tid == 0) counter[0] = 0;
    for (int i = tid; i < NUNITS; i += 256) flags[i] = 0;
    int n = tid;
    if (n < Nn) {
        float de[8], h[40];
#pragma unroll
        for (int k = 0; k < 8; ++k) de[k] = dem[n * 8 + k];
#pragma unroll
        for (int j = 0; j < 40; ++j) {
            float s = b1[j];
#pragma unroll
            for (int k = 0; k < 8; ++k) s += de[k] * W1[k * 40 + j];
            h[j] = fmaxf(s, 0.f);
        }
#pragma unroll
        for (int o = 0; o < 20; ++o) {
            float s = b2[o];
#pragma unroll
            for (int j = 0; j < 40; ++j) s += h[j] * W2[j * 20 + o];
            dvals[n * 20 + o] = fmaxf(s, 0.f);
        }
    }
}

// ---------------- fused aggregate + lookback + rescan + write ----------------
__global__ __launch_bounds__(256) void k_fused(
        const float* __restrict__ x0, const float* __restrict__ x1,
        const float* __restrict__ x2,
        f4* __restrict__ aggMax, i4* __restrict__ aggIdx, f4* __restrict__ aggSum,
        int* __restrict__ flags, int* __restrict__ counter,
        const float* __restrict__ dvals, float* __restrict__ out) {
    // ticket: vbid order == block entry order => any unit's predecessors
    // (smaller unit id) belong to blocks already entered => no deadlock.
    __shared__ int s_vbid;
    if (threadIdx.x == 0) s_vbid = atomicAdd(counter, 1);
    __syncthreads();
    int unit = s_vbid * 8 + (threadIdx.x >> 5);       // (inp, n, tile)
    int lane = threadIdx.x & 31;                      // channels lane*4..lane*4+3
    int inp = unit >> 10;                             // / (Nn*NTILES)=1024
    int rem = unit & 1023;
    int n = rem >> 5;                                 // / NTILES
    int tile = rem & 31;
    const float* x = (inp == 0) ? x0 : ((inp == 1) ? x1 : x2);
    int t0 = tile * TILE;
    const f4* p = (const f4*)(x + ((size_t)n * Ll + t0) * Cc) + lane;

    // ---- pass 1: local inclusive aggregate over own tile (x becomes cache-hot)
    f4 m = { -FLT_MAX, -FLT_MAX, -FLT_MAX, -FLT_MAX };
    i4 mi = { 0, 0, 0, 0 };
    f4 s = { 0.f, 0.f, 0.f, 0.f };
#pragma unroll 8
    for (int tl = 0; tl < TILE; ++tl) {
        f4 v = p[(size_t)tl * (Cc / 4)];
        int t = t0 + tl;
#pragma unroll
        for (int j = 0; j < 4; ++j) {
            s[j] += v[j];
            if (v[j] > m[j]) { m[j] = v[j]; mi[j] = t; }   // strict >: earlier wins ties
        }
    }

    // ---- publish: payload (plain stores), device fence, release flag
    int o = unit * (Cc / 4) + lane;
    aggMax[o] = m; aggIdx[o] = mi; aggSum[o] = s;
    __threadfence();
    if (lane == 0)
        __hip_atomic_store(&flags[unit], 1, __ATOMIC_RELEASE, __HIP_MEMORY_SCOPE_AGENT);

    // ---- wait for predecessors (one flag per lane, tile <= 31)
    int rowu = unit - tile;                            // first unit of this row
    if (lane < tile) {
        while (__hip_atomic_load(&flags[rowu + lane], __ATOMIC_RELAXED,
                                 __HIP_MEMORY_SCOPE_AGENT) == 0)
            __builtin_amdgcn_s_sleep(2);
    }
    __threadfence();                                   // acquire side: payload now safe

    // ---- carry merge (forward time order, strict > keeps earlier index)
    m = f4{ -FLT_MAX, -FLT_MAX, -FLT_MAX, -FLT_MAX };
    mi = i4{ 0, 0, 0, 0 };
    s = f4{ 0.f, 0.f, 0.f, 0.f };
    int rowbase = rowu * (Cc / 4) + lane;
#pragma unroll 4
    for (int j = 0; j < tile; ++j) {
        int po = rowbase + j * (Cc / 4);
        f4 am = aggMax[po]; i4 ai = aggIdx[po]; f4 as = aggSum[po];
#pragma unroll
        for (int jj = 0; jj < 4; ++jj) {
            if (am[jj] > m[jj]) { m[jj] = am[jj]; mi[jj] = ai[jj]; }
            s[jj] += as[jj];
        }
    }

    // MLP columns for this n (only inp==0 units broadcast them)
    float dv = 0.f;
    if (inp == 0 && lane < 20) dv = dvals[n * 20 + lane];

    // ---- pass 2: rescan own tile (L1/L2/L3-hot) and write outputs (all NT)
    f4* omax = (f4*)(out + (size_t)n * Ll * OUTC + (size_t)t0 * OUTC + inp * 384) + lane;
    f4* oind = (f4*)(out + OUT_ELEMS + (size_t)inp * NLC + ((size_t)n * Ll + t0) * Cc) + lane;
    f4* oact = (f4*)(out + OUT_ELEMS + 3 * (size_t)NLC + (size_t)inp * NLC + ((size_t)n * Ll + t0) * Cc) + lane;
    float* dout = out + (size_t)n * Ll * OUTC + (size_t)t0 * OUTC + 1152 + (lane < 20 ? lane : 0);

    const float invL = 1.0f / (float)Ll;
#pragma unroll 4
    for (int tl = 0; tl < TILE; ++tl) {
        f4 v = p[(size_t)tl * (Cc / 4)];
        int t = t0 + tl;
        bool haspad = (t < Ll - 1);
        float rcnt = __builtin_amdgcn_rcpf((float)(t + 1));   // ~1 ulp, within threshold
        f4 pmax, pidx, pavg, psum;
#pragma unroll
        for (int j = 0; j < 4; ++j) {
            s[j] += v[j];
            if (v[j] > m[j]) { m[j] = v[j]; mi[j] = t; }
            float cmax = m[j];
            pmax[j] = haspad ? fmaxf(cmax, 0.f) : cmax;
            pidx[j] = (float)((haspad && cmax < 0.f) ? (t - (Ll - 1)) : mi[j]);
            pavg[j] = s[j] * invL;
            psum[j] = s[j] * rcnt;
        }
        size_t ro = (size_t)tl * (OUTC / 4);
        nts4(&omax[ro],          pmax);
        nts4(&omax[ro + Cc / 4], pavg);   // +128 floats
        nts4(&omax[ro + Cc / 2], psum);   // +256 floats
        nts4(&oind[(size_t)tl * (Cc / 4)], pidx);
        nts4(&oact[(size_t)tl * (Cc / 4)], pmax);
        if (inp == 0 && lane < 20)
            nts1(&dout[(size_t)tl * OUTC], dv);   // coalesced 80 B row segment
    }
}

extern "C" void kernel_launch(void* const* d_in, const int* in_sizes, int n_in,
                              void* d_out, int out_size, void* d_ws, size_t ws_size,
                              hipStream_t stream) {
    const float* x0  = (const float*)d_in[0];
    const float* x1  = (const float*)d_in[1];
    const float* x2  = (const float*)d_in[2];
    const float* dem = (const float*)d_in[3];
    const float* W1  = (const float*)d_in[4];
    const float* b1  = (const float*)d_in[5];
    const float* W2  = (const float*)d_in[6];
    const float* b2  = (const float*)d_in[7];
    float* out = (float*)d_out;

    // ws layout: [counter 16B][flags NUNITS*4 = 12 KB][aggMax|aggIdx|aggSum 1.57 MB each][dvals]
    char* ws = (char*)d_ws;
    int*   counter = (int*)ws;
    int*   flags   = (int*)(ws + 16);
    char*  aggbase = ws + 16 + (size_t)NUNITS * 4;     // 12304, 16B-aligned
    float* aggMax = (float*)aggbase;
    int*   aggIdx = (int*)(aggbase + (size_t)AGG * 4);
    float* aggSum = (float*)(aggbase + 2 * (size_t)AGG * 4);
    float* dvals  = (float*)(aggbase + 3 * (size_t)AGG * 4);

    k_init<<<dim3(1), dim3(256), 0, stream>>>(counter, flags, dem, W1, b1, W2, b2, dvals);
    k_fused<<<dim3(NUNITS / 8), dim3(256), 0, stream>>>(x0, x1, x2,
        (f4*)aggMax, (i4*)aggIdx, (f4*)aggSum, flags, counter, dvals, out);
}